// Round 16
// baseline (1257.839 us; speedup 1.0000x reference)
//
#include <hip/hip_runtime.h>
#include <hip/hip_bf16.h>

#define DIM 128
#define G4 512      // 4*DIM
#define NL 4
#define VOCAB 32000
#define BB 32
#define SS 256
#define ROWS (BB*SS)   // 8192

typedef __attribute__((ext_vector_type(8))) short short8;
typedef __attribute__((ext_vector_type(4))) float f32x4;
typedef __attribute__((ext_vector_type(4))) unsigned int uint4v;
typedef __attribute__((ext_vector_type(2))) _Float16 h2;

__device__ __forceinline__ float fexp_(float x){ return __builtin_amdgcn_exp2f(x * 1.44269504088896f); }
__device__ __forceinline__ float frcp_(float x){ return __builtin_amdgcn_rcpf(x); }
__device__ __forceinline__ float sigm_(float x){ return frcp_(1.f + fexp_(-x)); }
__device__ __forceinline__ float tanh_(float x){
    float ax = fabsf(x);
    float e = fexp_(-2.f * ax);
    float t = (1.f - e) * frcp_(1.f + e);
    return x < 0.f ? -t : t;
}
__device__ __forceinline__ h2 mkh(float a, float b){ h2 r; r.x = (_Float16)a; r.y = (_Float16)b; return r; }
__device__ __forceinline__ unsigned long long f2bf_(float f){   // RNE -> bf16 bits
    unsigned u = __float_as_uint(f);
    u += 0x7fffu + ((u >> 16) & 1u);
    return (unsigned long long)(u >> 16);
}

#if __has_builtin(__builtin_amdgcn_fdot2)
#define FDOT2(w, d, acc) acc = __builtin_amdgcn_fdot2(w, d, acc, false);
#else
#define FDOT2(w, d, acc) acc = fmaf((float)(w).x, (float)(d).x, fmaf((float)(w).y, (float)(d).y, acc));
#endif
#define B2H(u) __builtin_bit_cast(h2, (unsigned)(u))

// ---- 32 named half2 regs (64 f16 weights = one K-half of one gate row) ----
#define WD32(p) h2 p##0,p##1,p##2,p##3,p##4,p##5,p##6,p##7,p##8,p##9,p##10,p##11, \
                   p##12,p##13,p##14,p##15,p##16,p##17,p##18,p##19,p##20,p##21,p##22,p##23, \
                   p##24,p##25,p##26,p##27,p##28,p##29,p##30,p##31;
#define WCVT32(p, src) { float4 t_; \
    t_=(src)[0];  p##0 =mkh(t_.x,t_.y); p##1 =mkh(t_.z,t_.w); \
    t_=(src)[1];  p##2 =mkh(t_.x,t_.y); p##3 =mkh(t_.z,t_.w); \
    t_=(src)[2];  p##4 =mkh(t_.x,t_.y); p##5 =mkh(t_.z,t_.w); \
    t_=(src)[3];  p##6 =mkh(t_.x,t_.y); p##7 =mkh(t_.z,t_.w); \
    t_=(src)[4];  p##8 =mkh(t_.x,t_.y); p##9 =mkh(t_.z,t_.w); \
    t_=(src)[5];  p##10=mkh(t_.x,t_.y); p##11=mkh(t_.z,t_.w); \
    t_=(src)[6];  p##12=mkh(t_.x,t_.y); p##13=mkh(t_.z,t_.w); \
    t_=(src)[7];  p##14=mkh(t_.x,t_.y); p##15=mkh(t_.z,t_.w); \
    t_=(src)[8];  p##16=mkh(t_.x,t_.y); p##17=mkh(t_.z,t_.w); \
    t_=(src)[9];  p##18=mkh(t_.x,t_.y); p##19=mkh(t_.z,t_.w); \
    t_=(src)[10]; p##20=mkh(t_.x,t_.y); p##21=mkh(t_.z,t_.w); \
    t_=(src)[11]; p##22=mkh(t_.x,t_.y); p##23=mkh(t_.z,t_.w); \
    t_=(src)[12]; p##24=mkh(t_.x,t_.y); p##25=mkh(t_.z,t_.w); \
    t_=(src)[13]; p##26=mkh(t_.x,t_.y); p##27=mkh(t_.z,t_.w); \
    t_=(src)[14]; p##28=mkh(t_.x,t_.y); p##29=mkh(t_.z,t_.w); \
    t_=(src)[15]; p##30=mkh(t_.x,t_.y); p##31=mkh(t_.z,t_.w); }
#define DT32(p, acc) \
    FDOT2(p##0,d0,acc)  FDOT2(p##1,d1,acc)  FDOT2(p##2,d2,acc)  FDOT2(p##3,d3,acc) \
    FDOT2(p##4,d4,acc)  FDOT2(p##5,d5,acc)  FDOT2(p##6,d6,acc)  FDOT2(p##7,d7,acc) \
    FDOT2(p##8,d8,acc)  FDOT2(p##9,d9,acc)  FDOT2(p##10,d10,acc) FDOT2(p##11,d11,acc) \
    FDOT2(p##12,d12,acc) FDOT2(p##13,d13,acc) FDOT2(p##14,d14,acc) FDOT2(p##15,d15,acc) \
    FDOT2(p##16,d16,acc) FDOT2(p##17,d17,acc) FDOT2(p##18,d18,acc) FDOT2(p##19,d19,acc) \
    FDOT2(p##20,d20,acc) FDOT2(p##21,d21,acc) FDOT2(p##22,d22,acc) FDOT2(p##23,d23,acc) \
    FDOT2(p##24,d24,acc) FDOT2(p##25,d25,acc) FDOT2(p##26,d26,acc) FDOT2(p##27,d27,acc) \
    FDOT2(p##28,d28,acc) FDOT2(p##29,d29,acc) FDOT2(p##30,d30,acc) FDOT2(p##31,d31,acc)
#define RD32(base) { const uint4v* hc_ = (const uint4v*)(base); \
    uint4v q0_=hc_[0], q1_=hc_[1], q2_=hc_[2], q3_=hc_[3], \
           q4_=hc_[4], q5_=hc_[5], q6_=hc_[6], q7_=hc_[7]; \
    d0=B2H(q0_.x); d1=B2H(q0_.y); d2=B2H(q0_.z); d3=B2H(q0_.w); \
    d4=B2H(q1_.x); d5=B2H(q1_.y); d6=B2H(q1_.z); d7=B2H(q1_.w); \
    d8=B2H(q2_.x); d9=B2H(q2_.y); d10=B2H(q2_.z); d11=B2H(q2_.w); \
    d12=B2H(q3_.x); d13=B2H(q3_.y); d14=B2H(q3_.z); d15=B2H(q3_.w); \
    d16=B2H(q4_.x); d17=B2H(q4_.y); d18=B2H(q4_.z); d19=B2H(q4_.w); \
    d20=B2H(q5_.x); d21=B2H(q5_.y); d22=B2H(q5_.z); d23=B2H(q5_.w); \
    d24=B2H(q6_.x); d25=B2H(q6_.y); d26=B2H(q6_.z); d27=B2H(q6_.w); \
    d28=B2H(q7_.x); d29=B2H(q7_.y); d30=B2H(q7_.z); d31=B2H(q7_.w); }

// full-K (128) fp32 macros for k_xw
#define W_DECL_ALL \
    float4 w0,w1,w2,w3,w4,w5,w6,w7,w8,w9,w10,w11,w12,w13,w14,w15, \
           w16,w17,w18,w19,w20,w21,w22,w23,w24,w25,w26,w27,w28,w29,w30,w31;
#define W_LOAD(i) w##i = wr[i];
#define W_LOAD_ALL \
    W_LOAD(0) W_LOAD(1) W_LOAD(2) W_LOAD(3) W_LOAD(4) W_LOAD(5) W_LOAD(6) W_LOAD(7) \
    W_LOAD(8) W_LOAD(9) W_LOAD(10) W_LOAD(11) W_LOAD(12) W_LOAD(13) W_LOAD(14) W_LOAD(15) \
    W_LOAD(16) W_LOAD(17) W_LOAD(18) W_LOAD(19) W_LOAD(20) W_LOAD(21) W_LOAD(22) W_LOAD(23) \
    W_LOAD(24) W_LOAD(25) W_LOAD(26) W_LOAD(27) W_LOAD(28) W_LOAD(29) W_LOAD(30) W_LOAD(31)
#define FMA1(i, acc) acc = fmaf(h4[i].x, w##i.x, fmaf(h4[i].y, w##i.y, \
                      fmaf(h4[i].z, w##i.z, fmaf(h4[i].w, w##i.w, acc))));
#define DOT128(a0,a1,a2,a3) \
    FMA1(0,a0) FMA1(1,a0) FMA1(2,a0) FMA1(3,a0) FMA1(4,a0) FMA1(5,a0) FMA1(6,a0) FMA1(7,a0) \
    FMA1(8,a1) FMA1(9,a1) FMA1(10,a1) FMA1(11,a1) FMA1(12,a1) FMA1(13,a1) FMA1(14,a1) FMA1(15,a1) \
    FMA1(16,a2) FMA1(17,a2) FMA1(18,a2) FMA1(19,a2) FMA1(20,a2) FMA1(21,a2) FMA1(22,a2) FMA1(23,a2) \
    FMA1(24,a3) FMA1(25,a3) FMA1(26,a3) FMA1(27,a3) FMA1(28,a3) FMA1(29,a3) FMA1(30,a3) FMA1(31,a3)

// ---------------- K0: zero the 16 chunk counters ----------------
__global__ void k_zero(int* __restrict__ f){ if (threadIdx.x < 16) f[threadIdx.x] = 0; }

// ---------------- K1: embedding gather ----------------
__global__ void k_embed(const int* __restrict__ x, const float* __restrict__ emb,
                        float* __restrict__ hseq){
    int i = blockIdx.x * blockDim.x + threadIdx.x;
    int row = i >> 5;
    int d4  = i & 31;
    int tok = x[row];
    ((float4*)hseq)[i] = ((const float4*)emb)[tok * 32 + d4];
}

// ---------------- K2: xw = hseq @ Wih^T + bih + bhh (cell-major layout) --------
__global__ __launch_bounds__(512, 2) void k_xw(const float* __restrict__ hseq,
                                               const float* Wih,
                                               const float* __restrict__ bih,
                                               const float* __restrict__ bhh,
                                               float* xw){
    __shared__ float hs[32 * DIM];
    int g = threadIdx.x;
    int r0 = blockIdx.x * 32;
    {
        const float4* src = (const float4*)(hseq + (size_t)r0 * DIM);
        float4* dst = (float4*)hs;
        for (int j = g; j < 32 * 32; j += 512) dst[j] = src[j];
    }
    int gg = ((g & 3) << 7) + (g >> 2);
    const float4* wr = (const float4*)(Wih + (size_t)gg * DIM);
    W_DECL_ALL
    W_LOAD_ALL
    float bias = bih[gg] + bhh[gg];
    __syncthreads();
    for (int r = 0; r < 32; ++r){
        const float4* h4 = (const float4*)(hs + r * DIM);
        float a0 = bias, a1 = 0.f, a2 = 0.f, a3 = 0.f;
        DOT128(a0, a1, a2, a3)
        xw[(size_t)(r0 + r) * G4 + g] = (a0 + a1) + (a2 + a3);
    }
}

// ---- R11-exact scan step macro (used by k_scan and k_tail scan role) ----
#define SCAN_STEP(XC, CH, I) { \
        h2 d0,d1,d2,d3,d4,d5,d6,d7,d8,d9,d10,d11,d12,d13,d14,d15, \
           d16,d17,d18,d19,d20,d21,d22,d23,d24,d25,d26,d27,d28,d29,d30,d31; \
        float s0 = XC.x, s1 = XC.y; \
        RD32(&hb[p][0]) \
        DT32(pA, s0) DT32(pC, s1) \
        RD32(&hb[p][64]) \
        DT32(pB, s0) DT32(pD, s1) \
        float o0 = __shfl_xor(s0, 1), o1 = __shfl_xor(s1, 1); \
        float i_pre = w ? o0 : s0, f_pre = w ? o1 : s1; \
        float g_pre = w ? s0 : o0, o_pre = w ? s1 : o1; \
        float iv = sigm_(i_pre), fv = sigm_(f_pre); \
        float gv = tanh_(g_pre), ov = sigm_(o_pre); \
        cc = fv * cc + iv * gv; \
        float h = ov * tanh_(cc); \
        if (!w) hb[p ^ 1][ci] = (_Float16)h; \
        else    stg[(CH) & 1][I][ci] = h; \
        __syncthreads(); \
        p ^= 1; }

// ---------------- K3: LSTM scan (layers 0..2) — R11-exact ----------------
__global__ __launch_bounds__(256, 1) void k_scan(const float* __restrict__ xw,
                                                 const float* Whh,
                                                 float* hseq){
    __shared__ _Float16 hb[2][DIM];
    __shared__ float    stg[2][16][DIM];
    const int tid = threadIdx.x;
    const int b = blockIdx.x;
    const int ci = tid >> 1;
    const int w  = tid & 1;

    WD32(pA) WD32(pB) WD32(pC) WD32(pD)
    {
        const float4* r0 = (const float4*)(Whh + (size_t)((2 * w    ) * DIM + ci) * DIM);
        const float4* r1 = (const float4*)(Whh + (size_t)((2 * w + 1) * DIM + ci) * DIM);
        WCVT32(pA, r0) WCVT32(pB, r0 + 16)
        WCVT32(pC, r1) WCVT32(pD, r1 + 16)
    }
    float cc = 0.f;
    if (tid < DIM) hb[0][tid] = (_Float16)0.f;
    const float2* xw2 = (const float2*)(xw + (size_t)b * SS * G4);
    float* hout = hseq + (size_t)b * SS * DIM;
    __syncthreads();
    int p = 0;

    for (int ch = 0; ch < 16; ++ch){
        if (ch > 0){
#pragma unroll
            for (int j = 0; j < 2; ++j){
                int idx = j * 256 + tid;
                int r = idx >> 5, c4 = idx & 31;
                float4 v = *(const float4*)&stg[(ch - 1) & 1][r][c4 * 4];
                *(float4*)(hout + (size_t)((ch - 1) * 16 + r) * DIM + c4 * 4) = v;
            }
        }
        const int t0 = ch * 16;
        float2 xc0  = xw2[(t0 +  0) * 256 + tid], xc1  = xw2[(t0 +  1) * 256 + tid],
               xc2  = xw2[(t0 +  2) * 256 + tid], xc3  = xw2[(t0 +  3) * 256 + tid],
               xc4  = xw2[(t0 +  4) * 256 + tid], xc5  = xw2[(t0 +  5) * 256 + tid],
               xc6  = xw2[(t0 +  6) * 256 + tid], xc7  = xw2[(t0 +  7) * 256 + tid],
               xc8  = xw2[(t0 +  8) * 256 + tid], xc9  = xw2[(t0 +  9) * 256 + tid],
               xc10 = xw2[(t0 + 10) * 256 + tid], xc11 = xw2[(t0 + 11) * 256 + tid],
               xc12 = xw2[(t0 + 12) * 256 + tid], xc13 = xw2[(t0 + 13) * 256 + tid],
               xc14 = xw2[(t0 + 14) * 256 + tid], xc15 = xw2[(t0 + 15) * 256 + tid];
        SCAN_STEP(xc0,  ch, 0)  SCAN_STEP(xc1,  ch, 1)  SCAN_STEP(xc2,  ch, 2)  SCAN_STEP(xc3,  ch, 3)
        SCAN_STEP(xc4,  ch, 4)  SCAN_STEP(xc5,  ch, 5)  SCAN_STEP(xc6,  ch, 6)  SCAN_STEP(xc7,  ch, 7)
        SCAN_STEP(xc8,  ch, 8)  SCAN_STEP(xc9,  ch, 9)  SCAN_STEP(xc10, ch, 10) SCAN_STEP(xc11, ch, 11)
        SCAN_STEP(xc12, ch, 12) SCAN_STEP(xc13, ch, 13) SCAN_STEP(xc14, ch, 14) SCAN_STEP(xc15, ch, 15)
    }
    {
#pragma unroll
        for (int j = 0; j < 2; ++j){
            int idx = j * 256 + tid;
            int r = idx >> 5, c4 = idx & 31;
            float4 v = *(const float4*)&stg[1][r][c4 * 4];
            *(float4*)(hout + (size_t)(240 + r) * DIM + c4 * 4) = v;
        }
    }
}

// ---------------- K5: head_W fp32 -> bf16 ----------------
__global__ void k_cvt(const float* __restrict__ w, __hip_bfloat16* __restrict__ wb){
    int i = blockIdx.x * blockDim.x + threadIdx.x;
    float4 v = ((const float4*)w)[i];
    __hip_bfloat162 p0, p1;
    p0.x = __float2bfloat16(v.x); p0.y = __float2bfloat16(v.y);
    p1.x = __float2bfloat16(v.z); p1.y = __float2bfloat16(v.w);
    ((__hip_bfloat162*)wb)[2 * i]     = p0;
    ((__hip_bfloat162*)wb)[2 * i + 1] = p1;
}

// ---------------- K6: fused layer-3 scan + LN + head ----------------
// 256 blocks x 256 thr, 1 block/CU FORCED via >80KB LDS -> all co-resident,
// scan blocks never share a CU with workers, no deadlock possible.
// Blocks 0..31: R11 scan step loop for layer 3 (batch b); per-chunk flush
//   computes LayerNorm inline (32-lane shfl row reduce) and publishes bf16 hn
//   rows via agent stores; after the flush drains at the next step's barrier,
//   tid0 does a RELEASE atomicAdd on gflag[chunk] (R3-proven protocol).
// Blocks 32..255: persistent head workers over 16000 tiles of 128x128.
//   Tile rows interleave 4 batches x 32 timesteps (g,t0) so the first tiles
//   unlock after 2/16 of the scan. Worker gating: ACQUIRE spin on
//   gflag[need-1]==32, only when need increases (t0-monotone order: 8 spins
//   total per worker). Head math/stores = R11-pinned (NT, ni-outer).
__global__ __launch_bounds__(256, 1) void k_tail(
    const float* __restrict__ xw, const float* Whh,
    const float* __restrict__ gamma, const float* __restrict__ beta,
    __hip_bfloat16* hnb,
    const __hip_bfloat16* __restrict__ wbp, const float* __restrict__ head_b,
    float* __restrict__ out, int* gflag, int dummy)
{
    __shared__ _Float16 hb[2][DIM];
    __shared__ float    stg[2][16][DIM];
    __shared__ f32x4    lds_pad[4096];   // 64 KB pad -> total >80 KB -> 1 block/CU
    const int tid = threadIdx.x;
    if (dummy) ((volatile float*)lds_pad)[tid] = 0.f;   // keep pad allocated

    if (blockIdx.x < 32){
        // ================= scan role (batch b) =================
        const int b = blockIdx.x;
        const int ci = tid >> 1;
        const int w  = tid & 1;
        WD32(pA) WD32(pB) WD32(pC) WD32(pD)
        {
            const float4* r0 = (const float4*)(Whh + (size_t)((2 * w    ) * DIM + ci) * DIM);
            const float4* r1 = (const float4*)(Whh + (size_t)((2 * w + 1) * DIM + ci) * DIM);
            WCVT32(pA, r0) WCVT32(pB, r0 + 16)
            WCVT32(pC, r1) WCVT32(pD, r1 + 16)
        }
        float cc = 0.f;
        if (tid < DIM) hb[0][tid] = (_Float16)0.f;
        const float2* xw2 = (const float2*)(xw + (size_t)b * SS * G4);
        unsigned long long* hn8 = (unsigned long long*)hnb;   // 32 qwords per row
        __syncthreads();
        int p = 0;

#define FLUSH_LN(C) { \
    _Pragma("unroll") \
    for (int j = 0; j < 2; ++j){ \
        int idx = j * 256 + tid; \
        int r = idx >> 5, c4 = idx & 31; \
        float4 v = *(const float4*)&stg[(C) & 1][r][c4 * 4]; \
        float s_ = (v.x + v.y) + (v.z + v.w); \
        float q_ = fmaf(v.x, v.x, fmaf(v.y, v.y, fmaf(v.z, v.z, v.w * v.w))); \
        s_ += __shfl_xor(s_, 1);  q_ += __shfl_xor(q_, 1); \
        s_ += __shfl_xor(s_, 2);  q_ += __shfl_xor(q_, 2); \
        s_ += __shfl_xor(s_, 4);  q_ += __shfl_xor(q_, 4); \
        s_ += __shfl_xor(s_, 8);  q_ += __shfl_xor(q_, 8); \
        s_ += __shfl_xor(s_, 16); q_ += __shfl_xor(q_, 16); \
        float mu_ = s_ * (1.f / 128.f); \
        float var_ = q_ * (1.f / 128.f) - mu_ * mu_; \
        float inv_ = rsqrtf(var_ + 1e-5f); \
        float4 gv_ = ((const float4*)gamma)[c4]; \
        float4 bv_ = ((const float4*)beta)[c4]; \
        unsigned long long bits = \
              f2bf_((v.x - mu_) * inv_ * gv_.x + bv_.x) \
            | (f2bf_((v.y - mu_) * inv_ * gv_.y + bv_.y) << 16) \
            | (f2bf_((v.z - mu_) * inv_ * gv_.z + bv_.z) << 32) \
            | (f2bf_((v.w - mu_) * inv_ * gv_.w + bv_.w) << 48); \
        int grow = b * 256 + (C) * 16 + r; \
        __hip_atomic_store(hn8 + (size_t)grow * 32 + c4, bits, \
                           __ATOMIC_RELAXED, __HIP_MEMORY_SCOPE_AGENT); \
    } }

        for (int ch = 0; ch < 16; ++ch){
            if (ch > 0) FLUSH_LN(ch - 1)
            const int t0 = ch * 16;
            float2 xc0  = xw2[(t0 +  0) * 256 + tid], xc1  = xw2[(t0 +  1) * 256 + tid],
                   xc2  = xw2[(t0 +  2) * 256 + tid], xc3  = xw2[(t0 +  3) * 256 + tid],
                   xc4  = xw2[(t0 +  4) * 256 + tid], xc5  = xw2[(t0 +  5) * 256 + tid],
                   xc6  = xw2[(t0 +  6) * 256 + tid], xc7  = xw2[(t0 +  7) * 256 + tid],
                   xc8  = xw2[(t0 +  8) * 256 + tid], xc9  = xw2[(t0 +  9) * 256 + tid],
                   xc10 = xw2[(t0 + 10) * 256 + tid], xc11 = xw2[(t0 + 11) * 256 + tid],
                   xc12 = xw2[(t0 + 12) * 256 + tid], xc13 = xw2[(t0 + 13) * 256 + tid],
                   xc14 = xw2[(t0 + 14) * 256 + tid], xc15 = xw2[(t0 + 15) * 256 + tid];
            SCAN_STEP(xc0,  ch, 0)
            // flush of chunk ch-1 has drained at the barrier above -> publish
            if (ch > 0 && tid == 0)
                __hip_atomic_fetch_add(&gflag[ch - 1], 1, __ATOMIC_RELEASE, __HIP_MEMORY_SCOPE_AGENT);
            SCAN_STEP(xc1,  ch, 1)  SCAN_STEP(xc2,  ch, 2)  SCAN_STEP(xc3,  ch, 3)
            SCAN_STEP(xc4,  ch, 4)  SCAN_STEP(xc5,  ch, 5)  SCAN_STEP(xc6,  ch, 6)  SCAN_STEP(xc7,  ch, 7)
            SCAN_STEP(xc8,  ch, 8)  SCAN_STEP(xc9,  ch, 9)  SCAN_STEP(xc10, ch, 10) SCAN_STEP(xc11, ch, 11)
            SCAN_STEP(xc12, ch, 12) SCAN_STEP(xc13, ch, 13) SCAN_STEP(xc14, ch, 14) SCAN_STEP(xc15, ch, 15)
        }
        FLUSH_LN(15)
        __syncthreads();   // drain final flush stores
        if (tid == 0)
            __hip_atomic_fetch_add(&gflag[15], 1, __ATOMIC_RELEASE, __HIP_MEMORY_SCOPE_AGENT);
#undef FLUSH_LN
    } else {
        // ================= head worker role =================
        // initial acquire: invalidate any pre-kernel stale cache lines of hn
        (void)__hip_atomic_load(&gflag[0], __ATOMIC_ACQUIRE, __HIP_MEMORY_SCOPE_AGENT);
        const int widx = blockIdx.x - 32;
        const int wid = tid >> 6, lane = tid & 63;
        const int wr = wid >> 1, wc = wid & 1;
        const int lrow = lane & 15, kgr = (lane >> 4) * 8;
        const int csub = (lane >> 4) * 4;
        const short* A  = (const short*)hnb;    // [8192][128] bf16 (published rows)
        const short* Bp = (const short*)wbp;    // [32000][128]
        int doneNeed = 0;
        for (int idx = widx; idx < 16000; idx += 224){
            const int t0 = idx / 2000;
            const int rr = idx % 2000;
            const int bn = rr >> 3, g = rr & 7;
            const int need = 2 * (t0 + 1);
            if (need > doneNeed){
                if (tid == 0){
                    while (__hip_atomic_load(&gflag[need - 1], __ATOMIC_ACQUIRE,
                                             __HIP_MEMORY_SCOPE_AGENT) < 32)
                        __builtin_amdgcn_s_sleep(8);
                }
                __syncthreads();
                doneNeed = need;
            }
            const int col0 = bn * 128 + wc * 64;
            const int rbase = (g * 4 + wr * 2) * 256 + t0 * 32;  // + (mi>>1)*256 + (mi&1)*16 + lrow
            f32x4 zero = {0.f, 0.f, 0.f, 0.f};
            f32x4 acc[4][4];
#pragma unroll
            for (int i = 0; i < 4; ++i)
#pragma unroll
                for (int j = 0; j < 4; ++j) acc[i][j] = zero;
#pragma unroll
            for (int ks = 0; ks < 4; ++ks){
                short8 a[4], bf[4];
#pragma unroll
                for (int mi = 0; mi < 4; ++mi){
                    int grow = rbase + (mi >> 1) * 256 + (mi & 1) * 16 + lrow;
                    a[mi] = *(const short8*)(A + (size_t)grow * DIM + ks * 32 + kgr);
                }
#pragma unroll
                for (int ni = 0; ni < 4; ++ni)
                    bf[ni] = *(const short8*)(Bp + (size_t)(col0 + ni * 16 + lrow) * DIM + ks * 32 + kgr);
#pragma unroll
                for (int mi = 0; mi < 4; ++mi)
#pragma unroll
                    for (int ni = 0; ni < 4; ++ni)
                        acc[mi][ni] = __builtin_amdgcn_mfma_f32_16x16x32_bf16(bf[ni], a[mi], acc[mi][ni], 0, 0, 0);
            }
#pragma unroll
            for (int ni = 0; ni < 4; ++ni){
                int cbase = col0 + ni * 16 + csub;
                float4 b4 = ((const float4*)head_b)[cbase >> 2];
#pragma unroll
                for (int mi = 0; mi < 4; ++mi){
                    int grow = rbase + (mi >> 1) * 256 + (mi & 1) * 16 + lrow;
                    f32x4 v;
                    v[0] = acc[mi][ni][0] + b4.x;
                    v[1] = acc[mi][ni][1] + b4.y;
                    v[2] = acc[mi][ni][2] + b4.z;
                    v[3] = acc[mi][ni][3] + b4.w;
                    __builtin_nontemporal_store(v, (f32x4*)(out + (size_t)grow * VOCAB + cbase));
                }
            }
        }
    }
}

extern "C" void kernel_launch(void* const* d_in, const int* in_sizes, int n_in,
                              void* d_out, int out_size, void* d_ws, size_t ws_size,
                              hipStream_t stream){
    const int*   x     = (const int*)  d_in[0];
    const float* emb   = (const float*)d_in[1];
    const float* Wih   = (const float*)d_in[2];
    const float* Whh   = (const float*)d_in[3];
    const float* bih   = (const float*)d_in[4];
    const float* bhh   = (const float*)d_in[5];
    const float* gamma = (const float*)d_in[6];
    const float* beta  = (const float*)d_in[7];
    const float* headW = (const float*)d_in[8];
    const float* headb = (const float*)d_in[9];
    float* out = (float*)d_out;

    char* ws = (char*)d_ws;
    float* xw   = (float*)ws;                                  // 16 MB [8192][512] (cell-major)
    float* hseq = (float*)(ws + (16u << 20));                  // 4 MB  [8192][128] (dead after xw l3)
    __hip_bfloat16* hn = (__hip_bfloat16*)(ws + (20u << 20));  // 2 MB
    __hip_bfloat16* wb = (__hip_bfloat16*)(ws + (22u << 20));  // 8 MB
    int* gflag = (int*)(ws + (16u << 20));                     // reuse hseq region (dead)

    const size_t WSZ = (size_t)G4 * DIM;

    k_embed<<<1024, 256, 0, stream>>>(x, emb, hseq);
    k_cvt  <<<4000, 256, 0, stream>>>(headW, wb);
    for (int l = 0; l < 3; ++l){
        k_xw  <<<256, 512, 0, stream>>>(hseq, Wih + (size_t)l * WSZ,
                                        bih + l * G4, bhh + l * G4, xw);
        k_scan<<<32, 256, 0, stream>>>(xw, Whh + (size_t)l * WSZ, hseq);
    }
    k_xw   <<<256, 512, 0, stream>>>(hseq, Wih + 3 * WSZ, bih + 3 * G4, bhh + 3 * G4, xw);
    k_zero <<<1, 64, 0, stream>>>(gflag);   // after xw l3 (gflag aliases hseq)
    k_tail <<<256, 256, 0, stream>>>(xw, Whh + 3 * WSZ, gamma, beta, hn,
                                     wb, headb, out, gflag, 0);
}

// Round 17
// 1251.428 us; speedup vs baseline: 1.0051x; 1.0051x over previous
//
#include <hip/hip_runtime.h>
#include <hip/hip_bf16.h>

#define DIM 128
#define G4 512      // 4*DIM
#define NL 4
#define VOCAB 32000
#define BB 32
#define SS 256
#define ROWS (BB*SS)   // 8192

typedef __attribute__((ext_vector_type(8))) short short8;
typedef __attribute__((ext_vector_type(4))) float f32x4;
typedef __attribute__((ext_vector_type(4))) unsigned int uint4v;
typedef __attribute__((ext_vector_type(2))) _Float16 h2;

__device__ __forceinline__ float fexp_(float x){ return __builtin_amdgcn_exp2f(x * 1.44269504088896f); }
__device__ __forceinline__ float frcp_(float x){ return __builtin_amdgcn_rcpf(x); }
__device__ __forceinline__ float sigm_(float x){ return frcp_(1.f + fexp_(-x)); }
__device__ __forceinline__ float tanh_(float x){
    float ax = fabsf(x);
    float e = fexp_(-2.f * ax);
    float t = (1.f - e) * frcp_(1.f + e);
    return x < 0.f ? -t : t;
}
__device__ __forceinline__ h2 mkh(float a, float b){ h2 r; r.x = (_Float16)a; r.y = (_Float16)b; return r; }
__device__ __forceinline__ unsigned long long f2bf_(float f){   // RNE -> bf16 bits
    unsigned u = __float_as_uint(f);
    u += 0x7fffu + ((u >> 16) & 1u);
    return (unsigned long long)(u >> 16);
}

#if __has_builtin(__builtin_amdgcn_fdot2)
#define FDOT2(w, d, acc) acc = __builtin_amdgcn_fdot2(w, d, acc, false);
#else
#define FDOT2(w, d, acc) acc = fmaf((float)(w).x, (float)(d).x, fmaf((float)(w).y, (float)(d).y, acc));
#endif
#define B2H(u) __builtin_bit_cast(h2, (unsigned)(u))

// ---- 32 named half2 regs (64 f16 weights = one K-half of one gate row) ----
#define WD32(p) h2 p##0,p##1,p##2,p##3,p##4,p##5,p##6,p##7,p##8,p##9,p##10,p##11, \
                   p##12,p##13,p##14,p##15,p##16,p##17,p##18,p##19,p##20,p##21,p##22,p##23, \
                   p##24,p##25,p##26,p##27,p##28,p##29,p##30,p##31;
#define WCVT32(p, src) { float4 t_; \
    t_=(src)[0];  p##0 =mkh(t_.x,t_.y); p##1 =mkh(t_.z,t_.w); \
    t_=(src)[1];  p##2 =mkh(t_.x,t_.y); p##3 =mkh(t_.z,t_.w); \
    t_=(src)[2];  p##4 =mkh(t_.x,t_.y); p##5 =mkh(t_.z,t_.w); \
    t_=(src)[3];  p##6 =mkh(t_.x,t_.y); p##7 =mkh(t_.z,t_.w); \
    t_=(src)[4];  p##8 =mkh(t_.x,t_.y); p##9 =mkh(t_.z,t_.w); \
    t_=(src)[5];  p##10=mkh(t_.x,t_.y); p##11=mkh(t_.z,t_.w); \
    t_=(src)[6];  p##12=mkh(t_.x,t_.y); p##13=mkh(t_.z,t_.w); \
    t_=(src)[7];  p##14=mkh(t_.x,t_.y); p##15=mkh(t_.z,t_.w); \
    t_=(src)[8];  p##16=mkh(t_.x,t_.y); p##17=mkh(t_.z,t_.w); \
    t_=(src)[9];  p##18=mkh(t_.x,t_.y); p##19=mkh(t_.z,t_.w); \
    t_=(src)[10]; p##20=mkh(t_.x,t_.y); p##21=mkh(t_.z,t_.w); \
    t_=(src)[11]; p##22=mkh(t_.x,t_.y); p##23=mkh(t_.z,t_.w); \
    t_=(src)[12]; p##24=mkh(t_.x,t_.y); p##25=mkh(t_.z,t_.w); \
    t_=(src)[13]; p##26=mkh(t_.x,t_.y); p##27=mkh(t_.z,t_.w); \
    t_=(src)[14]; p##28=mkh(t_.x,t_.y); p##29=mkh(t_.z,t_.w); \
    t_=(src)[15]; p##30=mkh(t_.x,t_.y); p##31=mkh(t_.z,t_.w); }
#define DT32(p, acc) \
    FDOT2(p##0,d0,acc)  FDOT2(p##1,d1,acc)  FDOT2(p##2,d2,acc)  FDOT2(p##3,d3,acc) \
    FDOT2(p##4,d4,acc)  FDOT2(p##5,d5,acc)  FDOT2(p##6,d6,acc)  FDOT2(p##7,d7,acc) \
    FDOT2(p##8,d8,acc)  FDOT2(p##9,d9,acc)  FDOT2(p##10,d10,acc) FDOT2(p##11,d11,acc) \
    FDOT2(p##12,d12,acc) FDOT2(p##13,d13,acc) FDOT2(p##14,d14,acc) FDOT2(p##15,d15,acc) \
    FDOT2(p##16,d16,acc) FDOT2(p##17,d17,acc) FDOT2(p##18,d18,acc) FDOT2(p##19,d19,acc) \
    FDOT2(p##20,d20,acc) FDOT2(p##21,d21,acc) FDOT2(p##22,d22,acc) FDOT2(p##23,d23,acc) \
    FDOT2(p##24,d24,acc) FDOT2(p##25,d25,acc) FDOT2(p##26,d26,acc) FDOT2(p##27,d27,acc) \
    FDOT2(p##28,d28,acc) FDOT2(p##29,d29,acc) FDOT2(p##30,d30,acc) FDOT2(p##31,d31,acc)
#define RD32(base) { const uint4v* hc_ = (const uint4v*)(base); \
    uint4v q0_=hc_[0], q1_=hc_[1], q2_=hc_[2], q3_=hc_[3], \
           q4_=hc_[4], q5_=hc_[5], q6_=hc_[6], q7_=hc_[7]; \
    d0=B2H(q0_.x); d1=B2H(q0_.y); d2=B2H(q0_.z); d3=B2H(q0_.w); \
    d4=B2H(q1_.x); d5=B2H(q1_.y); d6=B2H(q1_.z); d7=B2H(q1_.w); \
    d8=B2H(q2_.x); d9=B2H(q2_.y); d10=B2H(q2_.z); d11=B2H(q2_.w); \
    d12=B2H(q3_.x); d13=B2H(q3_.y); d14=B2H(q3_.z); d15=B2H(q3_.w); \
    d16=B2H(q4_.x); d17=B2H(q4_.y); d18=B2H(q4_.z); d19=B2H(q4_.w); \
    d20=B2H(q5_.x); d21=B2H(q5_.y); d22=B2H(q5_.z); d23=B2H(q5_.w); \
    d24=B2H(q6_.x); d25=B2H(q6_.y); d26=B2H(q6_.z); d27=B2H(q6_.w); \
    d28=B2H(q7_.x); d29=B2H(q7_.y); d30=B2H(q7_.z); d31=B2H(q7_.w); }

// full-K (128) fp32 macros for k_xw
#define W_DECL_ALL \
    float4 w0,w1,w2,w3,w4,w5,w6,w7,w8,w9,w10,w11,w12,w13,w14,w15, \
           w16,w17,w18,w19,w20,w21,w22,w23,w24,w25,w26,w27,w28,w29,w30,w31;
#define W_LOAD(i) w##i = wr[i];
#define W_LOAD_ALL \
    W_LOAD(0) W_LOAD(1) W_LOAD(2) W_LOAD(3) W_LOAD(4) W_LOAD(5) W_LOAD(6) W_LOAD(7) \
    W_LOAD(8) W_LOAD(9) W_LOAD(10) W_LOAD(11) W_LOAD(12) W_LOAD(13) W_LOAD(14) W_LOAD(15) \
    W_LOAD(16) W_LOAD(17) W_LOAD(18) W_LOAD(19) W_LOAD(20) W_LOAD(21) W_LOAD(22) W_LOAD(23) \
    W_LOAD(24) W_LOAD(25) W_LOAD(26) W_LOAD(27) W_LOAD(28) W_LOAD(29) W_LOAD(30) W_LOAD(31)
#define FMA1(i, acc) acc = fmaf(h4[i].x, w##i.x, fmaf(h4[i].y, w##i.y, \
                      fmaf(h4[i].z, w##i.z, fmaf(h4[i].w, w##i.w, acc))));
#define DOT128(a0,a1,a2,a3) \
    FMA1(0,a0) FMA1(1,a0) FMA1(2,a0) FMA1(3,a0) FMA1(4,a0) FMA1(5,a0) FMA1(6,a0) FMA1(7,a0) \
    FMA1(8,a1) FMA1(9,a1) FMA1(10,a1) FMA1(11,a1) FMA1(12,a1) FMA1(13,a1) FMA1(14,a1) FMA1(15,a1) \
    FMA1(16,a2) FMA1(17,a2) FMA1(18,a2) FMA1(19,a2) FMA1(20,a2) FMA1(21,a2) FMA1(22,a2) FMA1(23,a2) \
    FMA1(24,a3) FMA1(25,a3) FMA1(26,a3) FMA1(27,a3) FMA1(28,a3) FMA1(29,a3) FMA1(30,a3) FMA1(31,a3)

// ---------------- K0: zero the 16 chunk counters ----------------
__global__ void k_zero(int* __restrict__ f){ if (threadIdx.x < 16) f[threadIdx.x] = 0; }

// ---------------- K1: embedding gather ----------------
__global__ void k_embed(const int* __restrict__ x, const float* __restrict__ emb,
                        float* __restrict__ hseq){
    int i = blockIdx.x * blockDim.x + threadIdx.x;
    int row = i >> 5;
    int d4  = i & 31;
    int tok = x[row];
    ((float4*)hseq)[i] = ((const float4*)emb)[tok * 32 + d4];
}

// ---------------- K2: xw = hseq @ Wih^T + bih + bhh (cell-major layout) --------
__global__ __launch_bounds__(512, 2) void k_xw(const float* __restrict__ hseq,
                                               const float* Wih,
                                               const float* __restrict__ bih,
                                               const float* __restrict__ bhh,
                                               float* xw){
    __shared__ float hs[32 * DIM];
    int g = threadIdx.x;
    int r0 = blockIdx.x * 32;
    {
        const float4* src = (const float4*)(hseq + (size_t)r0 * DIM);
        float4* dst = (float4*)hs;
        for (int j = g; j < 32 * 32; j += 512) dst[j] = src[j];
    }
    int gg = ((g & 3) << 7) + (g >> 2);
    const float4* wr = (const float4*)(Wih + (size_t)gg * DIM);
    W_DECL_ALL
    W_LOAD_ALL
    float bias = bih[gg] + bhh[gg];
    __syncthreads();
    for (int r = 0; r < 32; ++r){
        const float4* h4 = (const float4*)(hs + r * DIM);
        float a0 = bias, a1 = 0.f, a2 = 0.f, a3 = 0.f;
        DOT128(a0, a1, a2, a3)
        xw[(size_t)(r0 + r) * G4 + g] = (a0 + a1) + (a2 + a3);
    }
}

// ---- R11-exact scan step macro (used by k_scan and k_tail scan role) ----
#define SCAN_STEP(XC, CH, I) { \
        h2 d0,d1,d2,d3,d4,d5,d6,d7,d8,d9,d10,d11,d12,d13,d14,d15, \
           d16,d17,d18,d19,d20,d21,d22,d23,d24,d25,d26,d27,d28,d29,d30,d31; \
        float s0 = XC.x, s1 = XC.y; \
        RD32(&hb[p][0]) \
        DT32(pA, s0) DT32(pC, s1) \
        RD32(&hb[p][64]) \
        DT32(pB, s0) DT32(pD, s1) \
        float o0 = __shfl_xor(s0, 1), o1 = __shfl_xor(s1, 1); \
        float i_pre = w ? o0 : s0, f_pre = w ? o1 : s1; \
        float g_pre = w ? s0 : o0, o_pre = w ? s1 : o1; \
        float iv = sigm_(i_pre), fv = sigm_(f_pre); \
        float gv = tanh_(g_pre), ov = sigm_(o_pre); \
        cc = fv * cc + iv * gv; \
        float h = ov * tanh_(cc); \
        if (!w) hb[p ^ 1][ci] = (_Float16)h; \
        else    stg[(CH) & 1][I][ci] = h; \
        __syncthreads(); \
        p ^= 1; }

// ---------------- K3: LSTM scan (layers 0..2) — R11-exact ----------------
__global__ __launch_bounds__(256, 1) void k_scan(const float* __restrict__ xw,
                                                 const float* Whh,
                                                 float* hseq){
    __shared__ _Float16 hb[2][DIM];
    __shared__ float    stg[2][16][DIM];
    const int tid = threadIdx.x;
    const int b = blockIdx.x;
    const int ci = tid >> 1;
    const int w  = tid & 1;

    WD32(pA) WD32(pB) WD32(pC) WD32(pD)
    {
        const float4* r0 = (const float4*)(Whh + (size_t)((2 * w    ) * DIM + ci) * DIM);
        const float4* r1 = (const float4*)(Whh + (size_t)((2 * w + 1) * DIM + ci) * DIM);
        WCVT32(pA, r0) WCVT32(pB, r0 + 16)
        WCVT32(pC, r1) WCVT32(pD, r1 + 16)
    }
    float cc = 0.f;
    if (tid < DIM) hb[0][tid] = (_Float16)0.f;
    const float2* xw2 = (const float2*)(xw + (size_t)b * SS * G4);
    float* hout = hseq + (size_t)b * SS * DIM;
    __syncthreads();
    int p = 0;

    for (int ch = 0; ch < 16; ++ch){
        if (ch > 0){
#pragma unroll
            for (int j = 0; j < 2; ++j){
                int idx = j * 256 + tid;
                int r = idx >> 5, c4 = idx & 31;
                float4 v = *(const float4*)&stg[(ch - 1) & 1][r][c4 * 4];
                *(float4*)(hout + (size_t)((ch - 1) * 16 + r) * DIM + c4 * 4) = v;
            }
        }
        const int t0 = ch * 16;
        float2 xc0  = xw2[(t0 +  0) * 256 + tid], xc1  = xw2[(t0 +  1) * 256 + tid],
               xc2  = xw2[(t0 +  2) * 256 + tid], xc3  = xw2[(t0 +  3) * 256 + tid],
               xc4  = xw2[(t0 +  4) * 256 + tid], xc5  = xw2[(t0 +  5) * 256 + tid],
               xc6  = xw2[(t0 +  6) * 256 + tid], xc7  = xw2[(t0 +  7) * 256 + tid],
               xc8  = xw2[(t0 +  8) * 256 + tid], xc9  = xw2[(t0 +  9) * 256 + tid],
               xc10 = xw2[(t0 + 10) * 256 + tid], xc11 = xw2[(t0 + 11) * 256 + tid],
               xc12 = xw2[(t0 + 12) * 256 + tid], xc13 = xw2[(t0 + 13) * 256 + tid],
               xc14 = xw2[(t0 + 14) * 256 + tid], xc15 = xw2[(t0 + 15) * 256 + tid];
        SCAN_STEP(xc0,  ch, 0)  SCAN_STEP(xc1,  ch, 1)  SCAN_STEP(xc2,  ch, 2)  SCAN_STEP(xc3,  ch, 3)
        SCAN_STEP(xc4,  ch, 4)  SCAN_STEP(xc5,  ch, 5)  SCAN_STEP(xc6,  ch, 6)  SCAN_STEP(xc7,  ch, 7)
        SCAN_STEP(xc8,  ch, 8)  SCAN_STEP(xc9,  ch, 9)  SCAN_STEP(xc10, ch, 10) SCAN_STEP(xc11, ch, 11)
        SCAN_STEP(xc12, ch, 12) SCAN_STEP(xc13, ch, 13) SCAN_STEP(xc14, ch, 14) SCAN_STEP(xc15, ch, 15)
    }
    {
#pragma unroll
        for (int j = 0; j < 2; ++j){
            int idx = j * 256 + tid;
            int r = idx >> 5, c4 = idx & 31;
            float4 v = *(const float4*)&stg[1][r][c4 * 4];
            *(float4*)(hout + (size_t)(240 + r) * DIM + c4 * 4) = v;
        }
    }
}

// ---------------- K5: head_W fp32 -> bf16 ----------------
__global__ void k_cvt(const float* __restrict__ w, __hip_bfloat16* __restrict__ wb){
    int i = blockIdx.x * blockDim.x + threadIdx.x;
    float4 v = ((const float4*)w)[i];
    __hip_bfloat162 p0, p1;
    p0.x = __float2bfloat16(v.x); p0.y = __float2bfloat16(v.y);
    p1.x = __float2bfloat16(v.z); p1.y = __float2bfloat16(v.w);
    ((__hip_bfloat162*)wb)[2 * i]     = p0;
    ((__hip_bfloat162*)wb)[2 * i + 1] = p1;
}

// ---------------- K6: fused layer-3 scan + LN + head (round-17: 2 blocks/CU) ---
// CHANGE vs R16: LDS pad removed (16.6 KB) + __launch_bounds__(256,2) (VGPR cap
// 256; scan path ~215 fits) -> 2 blocks/CU, 512 blocks all co-resident:
// 32 scan + 480 head workers. R16's head ran at 4 waves/CU (half MLP) and took
// ~460 us; at 8 waves/CU it should run ~230 us fully overlapped under the scan.
// Protocol (R16-proven correct): scan publishes LN'd bf16 rows (agent stores),
// release atomicAdd gflag[chunk] after the flush drains; workers acquire-spin
// once per t0 increase (t0-monotone tile order).
__global__ __launch_bounds__(256, 2) void k_tail(
    const float* __restrict__ xw, const float* Whh,
    const float* __restrict__ gamma, const float* __restrict__ beta,
    __hip_bfloat16* hnb,
    const __hip_bfloat16* __restrict__ wbp, const float* __restrict__ head_b,
    float* __restrict__ out, int* gflag, int dummy)
{
    __shared__ _Float16 hb[2][DIM];
    __shared__ float    stg[2][16][DIM];
    const int tid = threadIdx.x;

    if (blockIdx.x < 32){
        // ================= scan role (batch b) =================
        const int b = blockIdx.x;
        const int ci = tid >> 1;
        const int w  = tid & 1;
        WD32(pA) WD32(pB) WD32(pC) WD32(pD)
        {
            const float4* r0 = (const float4*)(Whh + (size_t)((2 * w    ) * DIM + ci) * DIM);
            const float4* r1 = (const float4*)(Whh + (size_t)((2 * w + 1) * DIM + ci) * DIM);
            WCVT32(pA, r0) WCVT32(pB, r0 + 16)
            WCVT32(pC, r1) WCVT32(pD, r1 + 16)
        }
        float cc = 0.f;
        if (tid < DIM) hb[0][tid] = (_Float16)0.f;
        const float2* xw2 = (const float2*)(xw + (size_t)b * SS * G4);
        unsigned long long* hn8 = (unsigned long long*)hnb;   // 32 qwords per row
        __syncthreads();
        int p = 0;

#define FLUSH_LN(C) { \
    _Pragma("unroll") \
    for (int j = 0; j < 2; ++j){ \
        int idx = j * 256 + tid; \
        int r = idx >> 5, c4 = idx & 31; \
        float4 v = *(const float4*)&stg[(C) & 1][r][c4 * 4]; \
        float s_ = (v.x + v.y) + (v.z + v.w); \
        float q_ = fmaf(v.x, v.x, fmaf(v.y, v.y, fmaf(v.z, v.z, v.w * v.w))); \
        s_ += __shfl_xor(s_, 1);  q_ += __shfl_xor(q_, 1); \
        s_ += __shfl_xor(s_, 2);  q_ += __shfl_xor(q_, 2); \
        s_ += __shfl_xor(s_, 4);  q_ += __shfl_xor(q_, 4); \
        s_ += __shfl_xor(s_, 8);  q_ += __shfl_xor(q_, 8); \
        s_ += __shfl_xor(s_, 16); q_ += __shfl_xor(q_, 16); \
        float mu_ = s_ * (1.f / 128.f); \
        float var_ = q_ * (1.f / 128.f) - mu_ * mu_; \
        float inv_ = rsqrtf(var_ + 1e-5f); \
        float4 gv_ = ((const float4*)gamma)[c4]; \
        float4 bv_ = ((const float4*)beta)[c4]; \
        unsigned long long bits = \
              f2bf_((v.x - mu_) * inv_ * gv_.x + bv_.x) \
            | (f2bf_((v.y - mu_) * inv_ * gv_.y + bv_.y) << 16) \
            | (f2bf_((v.z - mu_) * inv_ * gv_.z + bv_.z) << 32) \
            | (f2bf_((v.w - mu_) * inv_ * gv_.w + bv_.w) << 48); \
        int grow = b * 256 + (C) * 16 + r; \
        __hip_atomic_store(hn8 + (size_t)grow * 32 + c4, bits, \
                           __ATOMIC_RELAXED, __HIP_MEMORY_SCOPE_AGENT); \
    } }

        for (int ch = 0; ch < 16; ++ch){
            if (ch > 0) FLUSH_LN(ch - 1)
            const int t0 = ch * 16;
            float2 xc0  = xw2[(t0 +  0) * 256 + tid], xc1  = xw2[(t0 +  1) * 256 + tid],
                   xc2  = xw2[(t0 +  2) * 256 + tid], xc3  = xw2[(t0 +  3) * 256 + tid],
                   xc4  = xw2[(t0 +  4) * 256 + tid], xc5  = xw2[(t0 +  5) * 256 + tid],
                   xc6  = xw2[(t0 +  6) * 256 + tid], xc7  = xw2[(t0 +  7) * 256 + tid],
                   xc8  = xw2[(t0 +  8) * 256 + tid], xc9  = xw2[(t0 +  9) * 256 + tid],
                   xc10 = xw2[(t0 + 10) * 256 + tid], xc11 = xw2[(t0 + 11) * 256 + tid],
                   xc12 = xw2[(t0 + 12) * 256 + tid], xc13 = xw2[(t0 + 13) * 256 + tid],
                   xc14 = xw2[(t0 + 14) * 256 + tid], xc15 = xw2[(t0 + 15) * 256 + tid];
            SCAN_STEP(xc0,  ch, 0)
            // flush of chunk ch-1 has drained at the barrier above -> publish
            if (ch > 0 && tid == 0)
                __hip_atomic_fetch_add(&gflag[ch - 1], 1, __ATOMIC_RELEASE, __HIP_MEMORY_SCOPE_AGENT);
            SCAN_STEP(xc1,  ch, 1)  SCAN_STEP(xc2,  ch, 2)  SCAN_STEP(xc3,  ch, 3)
            SCAN_STEP(xc4,  ch, 4)  SCAN_STEP(xc5,  ch, 5)  SCAN_STEP(xc6,  ch, 6)  SCAN_STEP(xc7,  ch, 7)
            SCAN_STEP(xc8,  ch, 8)  SCAN_STEP(xc9,  ch, 9)  SCAN_STEP(xc10, ch, 10) SCAN_STEP(xc11, ch, 11)
            SCAN_STEP(xc12, ch, 12) SCAN_STEP(xc13, ch, 13) SCAN_STEP(xc14, ch, 14) SCAN_STEP(xc15, ch, 15)
        }
        FLUSH_LN(15)
        __syncthreads();   // drain final flush stores
        if (tid == 0)
            __hip_atomic_fetch_add(&gflag[15], 1, __ATOMIC_RELEASE, __HIP_MEMORY_SCOPE_AGENT);
#undef FLUSH_LN
    } else {
        // ================= head worker role =================
        (void)__hip_atomic_load(&gflag[0], __ATOMIC_ACQUIRE, __HIP_MEMORY_SCOPE_AGENT);
        const int widx = blockIdx.x - 32;       // 0..479
        const int wid = tid >> 6, lane = tid & 63;
        const int wr = wid >> 1, wc = wid & 1;
        const int lrow = lane & 15, kgr = (lane >> 4) * 8;
        const int csub = (lane >> 4) * 4;
        const short* A  = (const short*)hnb;    // [8192][128] bf16 (published rows)
        const short* Bp = (const short*)wbp;    // [32000][128]
        int doneNeed = 0;
        for (int idx = widx; idx < 16000; idx += 480){
            const int t0 = idx / 2000;
            const int rr = idx % 2000;
            const int bn = rr >> 3, g = rr & 7;
            const int need = 2 * (t0 + 1);
            if (need > doneNeed){
                if (tid == 0){
                    while (__hip_atomic_load(&gflag[need - 1], __ATOMIC_ACQUIRE,
                                             __HIP_MEMORY_SCOPE_AGENT) < 32)
                        __builtin_amdgcn_s_sleep(8);
                }
                __syncthreads();
                doneNeed = need;
            }
            const int col0 = bn * 128 + wc * 64;
            const int rbase = (g * 4 + wr * 2) * 256 + t0 * 32;
            f32x4 zero = {0.f, 0.f, 0.f, 0.f};
            f32x4 acc[4][4];
#pragma unroll
            for (int i = 0; i < 4; ++i)
#pragma unroll
                for (int j = 0; j < 4; ++j) acc[i][j] = zero;
#pragma unroll
            for (int ks = 0; ks < 4; ++ks){
                short8 a[4], bf[4];
#pragma unroll
                for (int mi = 0; mi < 4; ++mi){
                    int grow = rbase + (mi >> 1) * 256 + (mi & 1) * 16 + lrow;
                    a[mi] = *(const short8*)(A + (size_t)grow * DIM + ks * 32 + kgr);
                }
#pragma unroll
                for (int ni = 0; ni < 4; ++ni)
                    bf[ni] = *(const short8*)(Bp + (size_t)(col0 + ni * 16 + lrow) * DIM + ks * 32 + kgr);
#pragma unroll
                for (int mi = 0; mi < 4; ++mi)
#pragma unroll
                    for (int ni = 0; ni < 4; ++ni)
                        acc[mi][ni] = __builtin_amdgcn_mfma_f32_16x16x32_bf16(bf[ni], a[mi], acc[mi][ni], 0, 0, 0);
            }
#pragma unroll
            for (int ni = 0; ni < 4; ++ni){
                int cbase = col0 + ni * 16 + csub;
                float4 b4 = ((const float4*)head_b)[cbase >> 2];
#pragma unroll
                for (int mi = 0; mi < 4; ++mi){
                    int grow = rbase + (mi >> 1) * 256 + (mi & 1) * 16 + lrow;
                    f32x4 v;
                    v[0] = acc[mi][ni][0] + b4.x;
                    v[1] = acc[mi][ni][1] + b4.y;
                    v[2] = acc[mi][ni][2] + b4.z;
                    v[3] = acc[mi][ni][3] + b4.w;
                    __builtin_nontemporal_store(v, (f32x4*)(out + (size_t)grow * VOCAB + cbase));
                }
            }
        }
    }
}

extern "C" void kernel_launch(void* const* d_in, const int* in_sizes, int n_in,
                              void* d_out, int out_size, void* d_ws, size_t ws_size,
                              hipStream_t stream){
    const int*   x     = (const int*)  d_in[0];
    const float* emb   = (const float*)d_in[1];
    const float* Wih   = (const float*)d_in[2];
    const float* Whh   = (const float*)d_in[3];
    const float* bih   = (const float*)d_in[4];
    const float* bhh   = (const float*)d_in[5];
    const float* gamma = (const float*)d_in[6];
    const float* beta  = (const float*)d_in[7];
    const float* headW = (const float*)d_in[8];
    const float* headb = (const float*)d_in[9];
    float* out = (float*)d_out;

    char* ws = (char*)d_ws;
    float* xw   = (float*)ws;                                  // 16 MB [8192][512] (cell-major)
    float* hseq = (float*)(ws + (16u << 20));                  // 4 MB  (dead after xw l3)
    __hip_bfloat16* hn = (__hip_bfloat16*)(ws + (20u << 20));  // 2 MB
    __hip_bfloat16* wb = (__hip_bfloat16*)(ws + (22u << 20));  // 8 MB
    int* gflag = (int*)(ws + (16u << 20));                     // reuse hseq region (dead)

    const size_t WSZ = (size_t)G4 * DIM;

    k_embed<<<1024, 256, 0, stream>>>(x, emb, hseq);
    k_cvt  <<<4000, 256, 0, stream>>>(headW, wb);
    for (int l = 0; l < 3; ++l){
        k_xw  <<<256, 512, 0, stream>>>(hseq, Wih + (size_t)l * WSZ,
                                        bih + l * G4, bhh + l * G4, xw);
        k_scan<<<32, 256, 0, stream>>>(xw, Whh + (size_t)l * WSZ, hseq);
    }
    k_xw   <<<256, 512, 0, stream>>>(hseq, Wih + 3 * WSZ, bih + 3 * G4, bhh + 3 * G4, xw);
    k_zero <<<1, 64, 0, stream>>>(gflag);   // after xw l3 (gflag aliases hseq)
    k_tail <<<512, 256, 0, stream>>>(xw, Whh + 3 * WSZ, gamma, beta, hn,
                                     wb, headb, out, gflag, 0);
}

// Round 18
// 782.765 us; speedup vs baseline: 1.6069x; 1.5987x over previous
//
#include <hip/hip_runtime.h>
#include <hip/hip_bf16.h>

#define DIM 128
#define G4 512      // 4*DIM
#define NL 4
#define VOCAB 32000
#define BB 32
#define SS 256
#define ROWS (BB*SS)   // 8192

typedef __attribute__((ext_vector_type(8))) short short8;
typedef __attribute__((ext_vector_type(4))) float f32x4;
typedef __attribute__((ext_vector_type(4))) unsigned int uint4v;
typedef __attribute__((ext_vector_type(2))) _Float16 h2;

__device__ __forceinline__ float fexp_(float x){ return __builtin_amdgcn_exp2f(x * 1.44269504088896f); }
__device__ __forceinline__ float frcp_(float x){ return __builtin_amdgcn_rcpf(x); }
__device__ __forceinline__ float sigm_(float x){ return frcp_(1.f + fexp_(-x)); }
__device__ __forceinline__ float tanh_(float x){
    float ax = fabsf(x);
    float e = fexp_(-2.f * ax);
    float t = (1.f - e) * frcp_(1.f + e);
    return x < 0.f ? -t : t;
}
__device__ __forceinline__ h2 mkh(float a, float b){ h2 r; r.x = (_Float16)a; r.y = (_Float16)b; return r; }

#if __has_builtin(__builtin_amdgcn_fdot2)
#define FDOT2(w, d, acc) acc = __builtin_amdgcn_fdot2(w, d, acc, false);
#else
#define FDOT2(w, d, acc) acc = fmaf((float)(w).x, (float)(d).x, fmaf((float)(w).y, (float)(d).y, acc));
#endif
#define B2H(u) __builtin_bit_cast(h2, (unsigned)(u))
#define F2US(x) ((unsigned long long)__builtin_bit_cast(unsigned short, (_Float16)(x)))

// ---- 32 named half2 regs (64 f16 weights = one K-half of one gate row) ----
#define WD32(p) h2 p##0,p##1,p##2,p##3,p##4,p##5,p##6,p##7,p##8,p##9,p##10,p##11, \
                   p##12,p##13,p##14,p##15,p##16,p##17,p##18,p##19,p##20,p##21,p##22,p##23, \
                   p##24,p##25,p##26,p##27,p##28,p##29,p##30,p##31;
#define WCVT32(p, src) { float4 t_; \
    t_=(src)[0];  p##0 =mkh(t_.x,t_.y); p##1 =mkh(t_.z,t_.w); \
    t_=(src)[1];  p##2 =mkh(t_.x,t_.y); p##3 =mkh(t_.z,t_.w); \
    t_=(src)[2];  p##4 =mkh(t_.x,t_.y); p##5 =mkh(t_.z,t_.w); \
    t_=(src)[3];  p##6 =mkh(t_.x,t_.y); p##7 =mkh(t_.z,t_.w); \
    t_=(src)[4];  p##8 =mkh(t_.x,t_.y); p##9 =mkh(t_.z,t_.w); \
    t_=(src)[5];  p##10=mkh(t_.x,t_.y); p##11=mkh(t_.z,t_.w); \
    t_=(src)[6];  p##12=mkh(t_.x,t_.y); p##13=mkh(t_.z,t_.w); \
    t_=(src)[7];  p##14=mkh(t_.x,t_.y); p##15=mkh(t_.z,t_.w); \
    t_=(src)[8];  p##16=mkh(t_.x,t_.y); p##17=mkh(t_.z,t_.w); \
    t_=(src)[9];  p##18=mkh(t_.x,t_.y); p##19=mkh(t_.z,t_.w); \
    t_=(src)[10]; p##20=mkh(t_.x,t_.y); p##21=mkh(t_.z,t_.w); \
    t_=(src)[11]; p##22=mkh(t_.x,t_.y); p##23=mkh(t_.z,t_.w); \
    t_=(src)[12]; p##24=mkh(t_.x,t_.y); p##25=mkh(t_.z,t_.w); \
    t_=(src)[13]; p##26=mkh(t_.x,t_.y); p##27=mkh(t_.z,t_.w); \
    t_=(src)[14]; p##28=mkh(t_.x,t_.y); p##29=mkh(t_.z,t_.w); \
    t_=(src)[15]; p##30=mkh(t_.x,t_.y); p##31=mkh(t_.z,t_.w); }
#define DT32(p, acc) \
    FDOT2(p##0,d0,acc)  FDOT2(p##1,d1,acc)  FDOT2(p##2,d2,acc)  FDOT2(p##3,d3,acc) \
    FDOT2(p##4,d4,acc)  FDOT2(p##5,d5,acc)  FDOT2(p##6,d6,acc)  FDOT2(p##7,d7,acc) \
    FDOT2(p##8,d8,acc)  FDOT2(p##9,d9,acc)  FDOT2(p##10,d10,acc) FDOT2(p##11,d11,acc) \
    FDOT2(p##12,d12,acc) FDOT2(p##13,d13,acc) FDOT2(p##14,d14,acc) FDOT2(p##15,d15,acc) \
    FDOT2(p##16,d16,acc) FDOT2(p##17,d17,acc) FDOT2(p##18,d18,acc) FDOT2(p##19,d19,acc) \
    FDOT2(p##20,d20,acc) FDOT2(p##21,d21,acc) FDOT2(p##22,d22,acc) FDOT2(p##23,d23,acc) \
    FDOT2(p##24,d24,acc) FDOT2(p##25,d25,acc) FDOT2(p##26,d26,acc) FDOT2(p##27,d27,acc) \
    FDOT2(p##28,d28,acc) FDOT2(p##29,d29,acc) FDOT2(p##30,d30,acc) FDOT2(p##31,d31,acc)
#define RD32(base) { const uint4v* hc_ = (const uint4v*)(base); \
    uint4v q0_=hc_[0], q1_=hc_[1], q2_=hc_[2], q3_=hc_[3], \
           q4_=hc_[4], q5_=hc_[5], q6_=hc_[6], q7_=hc_[7]; \
    d0=B2H(q0_.x); d1=B2H(q0_.y); d2=B2H(q0_.z); d3=B2H(q0_.w); \
    d4=B2H(q1_.x); d5=B2H(q1_.y); d6=B2H(q1_.z); d7=B2H(q1_.w); \
    d8=B2H(q2_.x); d9=B2H(q2_.y); d10=B2H(q2_.z); d11=B2H(q2_.w); \
    d12=B2H(q3_.x); d13=B2H(q3_.y); d14=B2H(q3_.z); d15=B2H(q3_.w); \
    d16=B2H(q4_.x); d17=B2H(q4_.y); d18=B2H(q4_.z); d19=B2H(q4_.w); \
    d20=B2H(q5_.x); d21=B2H(q5_.y); d22=B2H(q5_.z); d23=B2H(q5_.w); \
    d24=B2H(q6_.x); d25=B2H(q6_.y); d26=B2H(q6_.z); d27=B2H(q6_.w); \
    d28=B2H(q7_.x); d29=B2H(q7_.y); d30=B2H(q7_.z); d31=B2H(q7_.w); }

// full-K (128) fp32 macros for k_xw (layer-0 only)
#define W_DECL_ALL \
    float4 w0,w1,w2,w3,w4,w5,w6,w7,w8,w9,w10,w11,w12,w13,w14,w15, \
           w16,w17,w18,w19,w20,w21,w22,w23,w24,w25,w26,w27,w28,w29,w30,w31;
#define W_LOAD(i) w##i = wr[i];
#define W_LOAD_ALL \
    W_LOAD(0) W_LOAD(1) W_LOAD(2) W_LOAD(3) W_LOAD(4) W_LOAD(5) W_LOAD(6) W_LOAD(7) \
    W_LOAD(8) W_LOAD(9) W_LOAD(10) W_LOAD(11) W_LOAD(12) W_LOAD(13) W_LOAD(14) W_LOAD(15) \
    W_LOAD(16) W_LOAD(17) W_LOAD(18) W_LOAD(19) W_LOAD(20) W_LOAD(21) W_LOAD(22) W_LOAD(23) \
    W_LOAD(24) W_LOAD(25) W_LOAD(26) W_LOAD(27) W_LOAD(28) W_LOAD(29) W_LOAD(30) W_LOAD(31)
#define FMA1(i, acc) acc = fmaf(h4[i].x, w##i.x, fmaf(h4[i].y, w##i.y, \
                      fmaf(h4[i].z, w##i.z, fmaf(h4[i].w, w##i.w, acc))));
#define DOT128(a0,a1,a2,a3) \
    FMA1(0,a0) FMA1(1,a0) FMA1(2,a0) FMA1(3,a0) FMA1(4,a0) FMA1(5,a0) FMA1(6,a0) FMA1(7,a0) \
    FMA1(8,a1) FMA1(9,a1) FMA1(10,a1) FMA1(11,a1) FMA1(12,a1) FMA1(13,a1) FMA1(14,a1) FMA1(15,a1) \
    FMA1(16,a2) FMA1(17,a2) FMA1(18,a2) FMA1(19,a2) FMA1(20,a2) FMA1(21,a2) FMA1(22,a2) FMA1(23,a2) \
    FMA1(24,a3) FMA1(25,a3) FMA1(26,a3) FMA1(27,a3) FMA1(28,a3) FMA1(29,a3) FMA1(30,a3) FMA1(31,a3)

// ---------------- K0: zero the 96 pipeline flags ----------------
__global__ void k_zero(int* __restrict__ f){ if (threadIdx.x < 96) f[threadIdx.x] = 0; }

// ---------------- K1: embedding gather ----------------
__global__ void k_embed(const int* __restrict__ x, const float* __restrict__ emb,
                        float* __restrict__ hseq){
    int i = blockIdx.x * blockDim.x + threadIdx.x;
    int row = i >> 5;
    int d4  = i & 31;
    int tok = x[row];
    ((float4*)hseq)[i] = ((const float4*)emb)[tok * 32 + d4];
}

// ---------------- K2: xw0 = hseq @ Wih0^T + b (layer 0 ONLY, cell-major) -------
__global__ __launch_bounds__(512, 2) void k_xw(const float* __restrict__ hseq,
                                               const float* Wih,
                                               const float* __restrict__ bih,
                                               const float* __restrict__ bhh,
                                               float* xw){
    __shared__ float hs[32 * DIM];
    int g = threadIdx.x;
    int r0 = blockIdx.x * 32;
    {
        const float4* src = (const float4*)(hseq + (size_t)r0 * DIM);
        float4* dst = (float4*)hs;
        for (int j = g; j < 32 * 32; j += 512) dst[j] = src[j];
    }
    int gg = ((g & 3) << 7) + (g >> 2);
    const float4* wr = (const float4*)(Wih + (size_t)gg * DIM);
    W_DECL_ALL
    W_LOAD_ALL
    float bias = bih[gg] + bhh[gg];
    __syncthreads();
    for (int r = 0; r < 32; ++r){
        const float4* h4 = (const float4*)(hs + r * DIM);
        float a0 = bias, a1 = 0.f, a2 = 0.f, a3 = 0.f;
        DOT128(a0, a1, a2, a3)
        xw[(size_t)(r0 + r) * G4 + g] = (a0 + a1) + (a2 + a3);
    }
}

// ---- R11-exact scan step ----
#define SCAN_STEP(XC, CH, I) { \
        h2 d0,d1,d2,d3,d4,d5,d6,d7,d8,d9,d10,d11,d12,d13,d14,d15, \
           d16,d17,d18,d19,d20,d21,d22,d23,d24,d25,d26,d27,d28,d29,d30,d31; \
        float s0 = XC.x, s1 = XC.y; \
        RD32(&hb[p][0]) \
        DT32(pA, s0) DT32(pC, s1) \
        RD32(&hb[p][64]) \
        DT32(pB, s0) DT32(pD, s1) \
        float o0 = __shfl_xor(s0, 1), o1 = __shfl_xor(s1, 1); \
        float i_pre = w ? o0 : s0, f_pre = w ? o1 : s1; \
        float g_pre = w ? s0 : o0, o_pre = w ? s1 : o1; \
        float iv = sigm_(i_pre), fv = sigm_(f_pre); \
        float gv = tanh_(g_pre), ov = sigm_(o_pre); \
        cc = fv * cc + iv * gv; \
        float h = ov * tanh_(cc); \
        if (!w) hb[p ^ 1][ci] = (_Float16)h; \
        else    stg[(CH) & 1][I][ci] = h; \
        __syncthreads(); \
        p ^= 1; }

// next-layer input dot: xw(next chunk, step I) for this thread's 2 gates,
// from the staged producer chunk hp (independent of the scan chain -> fills
// the step's latency bubbles).
#define XN_DOT(I) { \
        h2 d0,d1,d2,d3,d4,d5,d6,d7,d8,d9,d10,d11,d12,d13,d14,d15, \
           d16,d17,d18,d19,d20,d21,d22,d23,d24,d25,d26,d27,d28,d29,d30,d31; \
        float nx = biasv.x, ny = biasv.y; \
        RD32(hpF + (I) * 128) \
        DT32(pE, nx) DT32(pG, ny) \
        RD32(hpF + (I) * 128 + 64) \
        DT32(pF, nx) DT32(pH, ny) \
        xn##I.x = nx; xn##I.y = ny; }

// ---------------- K3: fused 4-layer pipelined scan ----------------
// 128 blocks (l = bid>>5, b = bid&31) x 256 thr, 1 block/CU, all co-resident,
// NO CU sharing (the R16/R17 contention failure mode is structurally excluded).
// l=0: R11 scan (xw from global xw0), publishes f16 h chunks (agent qword
//      stores) + release flag per chunk.
// l=1,2: consumer (stage producer chunk via acquire flag, compute own xw
//      interleaved into scan steps) + publisher.
// l=3: consumer; flushes fp32 h to hseq for LN/head.
// Protocol per R3/R16: stores -> __syncthreads (vmcnt drain) -> release store;
// consumer: tid0 acquire spin -> __syncthreads -> relaxed agent loads.
__global__ __launch_bounds__(256, 1) void k_fused(
    const float* __restrict__ xw0,
    const float* Wih, const float* Whh,
    const float* __restrict__ bih, const float* __restrict__ bhh,
    unsigned long long* hf16,     // [3][32][256][32] qwords (f16 h transport)
    float* hseq3,                 // [32][256][128] fp32 (layer-3 out)
    int* flags)                   // [3][32] monotone chunk counters
{
    __shared__ _Float16 hb[2][DIM];
    __shared__ float    stg[2][16][DIM];
    __shared__ __align__(16) unsigned long long hp[512];   // staged producer chunk (4 KB)
    const int tid = threadIdx.x;
    const int l = blockIdx.x >> 5, b = blockIdx.x & 31;
    const int ci = tid >> 1, w = tid & 1;
    const _Float16* hpF = (const _Float16*)hp;

    WD32(pA) WD32(pB) WD32(pC) WD32(pD)   // Whh rows 2w,2w+1 of cell ci
    {
        const float* Wl = Whh + (size_t)l * G4 * DIM;
        const float4* r0 = (const float4*)(Wl + (size_t)((2 * w    ) * DIM + ci) * DIM);
        const float4* r1 = (const float4*)(Wl + (size_t)((2 * w + 1) * DIM + ci) * DIM);
        WCVT32(pA, r0) WCVT32(pB, r0 + 16)
        WCVT32(pC, r1) WCVT32(pD, r1 + 16)
    }
    WD32(pE) WD32(pF) WD32(pG) WD32(pH)   // Wih rows (consumers only)
    float2 biasv = {0.f, 0.f};
    if (l > 0){
        const float* Vl = Wih + (size_t)l * G4 * DIM;
        const float4* q0 = (const float4*)(Vl + (size_t)((2 * w    ) * DIM + ci) * DIM);
        const float4* q1 = (const float4*)(Vl + (size_t)((2 * w + 1) * DIM + ci) * DIM);
        WCVT32(pE, q0) WCVT32(pF, q0 + 16)
        WCVT32(pG, q1) WCVT32(pH, q1 + 16)
        biasv.x = bih[l * G4 + (2 * w    ) * DIM + ci] + bhh[l * G4 + (2 * w    ) * DIM + ci];
        biasv.y = bih[l * G4 + (2 * w + 1) * DIM + ci] + bhh[l * G4 + (2 * w + 1) * DIM + ci];
    }
    unsigned long long*       pub = hf16 + (size_t)(l * 32 + b) * 8192;        // producer slot
    const unsigned long long* src = hf16 + (size_t)((l - 1) * 32 + b) * 8192;  // consumer slot
    int* myflag = flags + (l * 32 + b);
    const int* inflag = flags + ((l - 1) * 32 + b);
    const float2* xw2 = (const float2*)(xw0 + (size_t)b * SS * G4);
    float* hout = hseq3 + (size_t)b * SS * DIM;

    float cc = 0.f;
    if (tid < DIM) hb[0][tid] = (_Float16)0.f;
    __syncthreads();
    int p = 0;
    int seen = 0;
    float2 xq0,xq1,xq2,xq3,xq4,xq5,xq6,xq7,xq8,xq9,xq10,xq11,xq12,xq13,xq14,xq15;
    float2 xn0,xn1,xn2,xn3,xn4,xn5,xn6,xn7,xn8,xn9,xn10,xn11,xn12,xn13,xn14,xn15;

#define BLOCK_WAIT(TGT) { int t_ = (TGT); if (seen < t_){ \
        if (tid == 0){ while (__hip_atomic_load(inflag, __ATOMIC_ACQUIRE, \
            __HIP_MEMORY_SCOPE_AGENT) < t_) __builtin_amdgcn_s_sleep(4); } \
        __syncthreads(); seen = t_; } }
#define STAGE(C) { const unsigned long long* s_ = src + (size_t)(C) * 512; \
        hp[tid]       = __hip_atomic_load(s_ + tid,       __ATOMIC_RELAXED, __HIP_MEMORY_SCOPE_AGENT); \
        hp[tid + 256] = __hip_atomic_load(s_ + tid + 256, __ATOMIC_RELAXED, __HIP_MEMORY_SCOPE_AGENT); }
#define FLUSH_PUB(C) { \
    _Pragma("unroll") \
    for (int j = 0; j < 2; ++j){ \
        int idx = j * 256 + tid; \
        int r = idx >> 5, c4 = idx & 31; \
        float4 v = *(const float4*)&stg[(C) & 1][r][c4 * 4]; \
        unsigned long long bits = F2US(v.x) | (F2US(v.y) << 16) | (F2US(v.z) << 32) | (F2US(v.w) << 48); \
        __hip_atomic_store(pub + (size_t)((C) * 16 + r) * 32 + c4, bits, \
                           __ATOMIC_RELAXED, __HIP_MEMORY_SCOPE_AGENT); \
    } }
#define FLUSH_F32(C) { \
    _Pragma("unroll") \
    for (int j = 0; j < 2; ++j){ \
        int idx = j * 256 + tid; \
        int r = idx >> 5, c4 = idx & 31; \
        float4 v = *(const float4*)&stg[(C) & 1][r][c4 * 4]; \
        *(float4*)(hout + (size_t)((C) * 16 + r) * DIM + c4 * 4) = v; \
    } }
#define XQ_FROM_XN \
    xq0=xn0; xq1=xn1; xq2=xn2; xq3=xn3; xq4=xn4; xq5=xn5; xq6=xn6; xq7=xn7; \
    xq8=xn8; xq9=xn9; xq10=xn10; xq11=xn11; xq12=xn12; xq13=xn13; xq14=xn14; xq15=xn15;

    if (l > 0){
        // prologue: stage chunk 0, burst-compute xw(chunk 0)
        BLOCK_WAIT(1)
        STAGE(0)
        __syncthreads();
        XN_DOT(0)  XN_DOT(1)  XN_DOT(2)  XN_DOT(3)  XN_DOT(4)  XN_DOT(5)  XN_DOT(6)  XN_DOT(7)
        XN_DOT(8)  XN_DOT(9)  XN_DOT(10) XN_DOT(11) XN_DOT(12) XN_DOT(13) XN_DOT(14) XN_DOT(15)
        XQ_FROM_XN
    }

#pragma unroll 1
    for (int c = 0; c < 16; ++c){
        if (c > 0){
            if (l < 3) FLUSH_PUB(c - 1)
            else       FLUSH_F32(c - 1)
        }
        if (l == 0){
            const int t0 = c * 16;
            xq0  = xw2[(t0 +  0) * 256 + tid]; xq1  = xw2[(t0 +  1) * 256 + tid];
            xq2  = xw2[(t0 +  2) * 256 + tid]; xq3  = xw2[(t0 +  3) * 256 + tid];
            xq4  = xw2[(t0 +  4) * 256 + tid]; xq5  = xw2[(t0 +  5) * 256 + tid];
            xq6  = xw2[(t0 +  6) * 256 + tid]; xq7  = xw2[(t0 +  7) * 256 + tid];
            xq8  = xw2[(t0 +  8) * 256 + tid]; xq9  = xw2[(t0 +  9) * 256 + tid];
            xq10 = xw2[(t0 + 10) * 256 + tid]; xq11 = xw2[(t0 + 11) * 256 + tid];
            xq12 = xw2[(t0 + 12) * 256 + tid]; xq13 = xw2[(t0 + 13) * 256 + tid];
            xq14 = xw2[(t0 + 14) * 256 + tid]; xq15 = xw2[(t0 + 15) * 256 + tid];
        } else if (c < 15){
            BLOCK_WAIT(c + 2)
            STAGE(c + 1)
        }
        __syncthreads();   // drains flush stores + staging writes (+ xq loads partly)
        if (l < 3 && c > 0 && tid == 0)
            __hip_atomic_store(myflag, c, __ATOMIC_RELEASE, __HIP_MEMORY_SCOPE_AGENT);
        const bool doXN = (l > 0) && (c < 15);
        if (doXN) XN_DOT(0)   SCAN_STEP(xq0,  c, 0)
        if (doXN) XN_DOT(1)   SCAN_STEP(xq1,  c, 1)
        if (doXN) XN_DOT(2)   SCAN_STEP(xq2,  c, 2)
        if (doXN) XN_DOT(3)   SCAN_STEP(xq3,  c, 3)
        if (doXN) XN_DOT(4)   SCAN_STEP(xq4,  c, 4)
        if (doXN) XN_DOT(5)   SCAN_STEP(xq5,  c, 5)
        if (doXN) XN_DOT(6)   SCAN_STEP(xq6,  c, 6)
        if (doXN) XN_DOT(7)   SCAN_STEP(xq7,  c, 7)
        if (doXN) XN_DOT(8)   SCAN_STEP(xq8,  c, 8)
        if (doXN) XN_DOT(9)   SCAN_STEP(xq9,  c, 9)
        if (doXN) XN_DOT(10)  SCAN_STEP(xq10, c, 10)
        if (doXN) XN_DOT(11)  SCAN_STEP(xq11, c, 11)
        if (doXN) XN_DOT(12)  SCAN_STEP(xq12, c, 12)
        if (doXN) XN_DOT(13)  SCAN_STEP(xq13, c, 13)
        if (doXN) XN_DOT(14)  SCAN_STEP(xq14, c, 14)
        if (doXN) XN_DOT(15)  SCAN_STEP(xq15, c, 15)
        if (doXN){ XQ_FROM_XN }
    }
    if (l < 3){
        FLUSH_PUB(15)
        __syncthreads();
        if (tid == 0)
            __hip_atomic_store(myflag, 16, __ATOMIC_RELEASE, __HIP_MEMORY_SCOPE_AGENT);
    } else {
        FLUSH_F32(15)
    }
#undef BLOCK_WAIT
#undef STAGE
#undef FLUSH_PUB
#undef FLUSH_F32
#undef XQ_FROM_XN
}

// ---------------- K4: LayerNorm -> bf16 ----------------
__global__ void k_ln(const float* __restrict__ hseq, const float* __restrict__ gamma,
                     const float* __restrict__ beta, __hip_bfloat16* __restrict__ hn){
    int wid = threadIdx.x >> 6;
    int lane = threadIdx.x & 63;
    int row = blockIdx.x * 4 + wid;
    float2 hv = ((const float2*)(hseq + (size_t)row * DIM))[lane];
    float s = hv.x + hv.y;
    float sq = fmaf(hv.x, hv.x, hv.y * hv.y);
    for (int off = 32; off; off >>= 1){ s += __shfl_xor(s, off); sq += __shfl_xor(sq, off); }
    float mu = s * (1.f / 128.f);
    float var = sq * (1.f / 128.f) - mu * mu;
    float inv = rsqrtf(var + 1e-5f);
    float2 gv = ((const float2*)gamma)[lane];
    float2 bv = ((const float2*)beta)[lane];
    __hip_bfloat162 pr;
    pr.x = __float2bfloat16((hv.x - mu) * inv * gv.x + bv.x);
    pr.y = __float2bfloat16((hv.y - mu) * inv * gv.y + bv.y);
    ((__hip_bfloat162*)hn)[(size_t)row * 64 + lane] = pr;
}

// ---------------- K5: head_W fp32 -> bf16 ----------------
__global__ void k_cvt(const float* __restrict__ w, __hip_bfloat16* __restrict__ wb){
    int i = blockIdx.x * blockDim.x + threadIdx.x;
    float4 v = ((const float4*)w)[i];
    __hip_bfloat162 p0, p1;
    p0.x = __float2bfloat16(v.x); p0.y = __float2bfloat16(v.y);
    p1.x = __float2bfloat16(v.z); p1.y = __float2bfloat16(v.w);
    ((__hip_bfloat162*)wb)[2 * i]     = p0;
    ((__hip_bfloat162*)wb)[2 * i + 1] = p1;
}

// ---------------- K6: head GEMM — R11-exact (128x128, NT stores, ni-outer) -----
__global__ __launch_bounds__(256) void k_head(const __hip_bfloat16* __restrict__ hn,
                                              const __hip_bfloat16* __restrict__ wb,
                                              const float* __restrict__ head_b,
                                              float* __restrict__ out){
    int bn = blockIdx.x;
    int bm = blockIdx.y;
    int wid = threadIdx.x >> 6;
    int lane = threadIdx.x & 63;
    int wr = wid >> 1, wc = wid & 1;
    int row0 = bm * 128 + wr * 64;
    int col0 = bn * 128 + wc * 64;
    const short* A  = (const short*)hn;
    const short* Bp = (const short*)wb;
    f32x4 zero = {0.f, 0.f, 0.f, 0.f};
    f32x4 acc[4][4];
#pragma unroll
    for (int i = 0; i < 4; ++i)
#pragma unroll
        for (int j = 0; j < 4; ++j) acc[i][j] = zero;
    int lrow = lane & 15;
    int kgr = (lane >> 4) * 8;
#pragma unroll
    for (int ks = 0; ks < 4; ++ks){
        short8 a[4], bf[4];
#pragma unroll
        for (int mi = 0; mi < 4; ++mi)
            a[mi] = *(const short8*)(A + (size_t)(row0 + mi * 16 + lrow) * DIM + ks * 32 + kgr);
#pragma unroll
        for (int ni = 0; ni < 4; ++ni)
            bf[ni] = *(const short8*)(Bp + (size_t)(col0 + ni * 16 + lrow) * DIM + ks * 32 + kgr);
#pragma unroll
        for (int mi = 0; mi < 4; ++mi)
#pragma unroll
            for (int ni = 0; ni < 4; ++ni)
                acc[mi][ni] = __builtin_amdgcn_mfma_f32_16x16x32_bf16(bf[ni], a[mi], acc[mi][ni], 0, 0, 0);
    }
    int csub = (lane >> 4) * 4;
#pragma unroll
    for (int ni = 0; ni < 4; ++ni){
        int cbase = col0 + ni * 16 + csub;
        float4 b4 = ((const float4*)head_b)[cbase >> 2];
#pragma unroll
        for (int mi = 0; mi < 4; ++mi){
            int row = row0 + mi * 16 + lrow;
            f32x4 v;
            v[0] = acc[mi][ni][0] + b4.x;
            v[1] = acc[mi][ni][1] + b4.y;
            v[2] = acc[mi][ni][2] + b4.z;
            v[3] = acc[mi][ni][3] + b4.w;
            __builtin_nontemporal_store(v, (f32x4*)(out + (size_t)row * VOCAB + cbase));
        }
    }
}

extern "C" void kernel_launch(void* const* d_in, const int* in_sizes, int n_in,
                              void* d_out, int out_size, void* d_ws, size_t ws_size,
                              hipStream_t stream){
    const int*   x     = (const int*)  d_in[0];
    const float* emb   = (const float*)d_in[1];
    const float* Wih   = (const float*)d_in[2];
    const float* Whh   = (const float*)d_in[3];
    const float* bih   = (const float*)d_in[4];
    const float* bhh   = (const float*)d_in[5];
    const float* gamma = (const float*)d_in[6];
    const float* beta  = (const float*)d_in[7];
    const float* headW = (const float*)d_in[8];
    const float* headb = (const float*)d_in[9];
    float* out = (float*)d_out;

    char* ws = (char*)d_ws;
    float* xw0  = (float*)ws;                                  // 16 MB [8192][512] (cell-major)
    float* hseq = (float*)(ws + (16u << 20));                  // 4 MB: embed out, then layer-3 h out
    __hip_bfloat16* hn = (__hip_bfloat16*)(ws + (20u << 20));  // 2 MB
    __hip_bfloat16* wb = (__hip_bfloat16*)(ws + (22u << 20));  // 8 MB

    // pipeline transport in the FRONT of d_out (overwritten by k_head after)
    char* ob = (char*)d_out;
    unsigned long long* hf16 = (unsigned long long*)ob;        // 6 MB [3][32][256][32] qwords
    int* flags = (int*)(ob + (6u << 20));                      // 96 ints

    k_embed<<<1024, 256, 0, stream>>>(x, emb, hseq);
    k_cvt  <<<4000, 256, 0, stream>>>(headW, wb);
    k_xw   <<<256, 512, 0, stream>>>(hseq, Wih, bih, bhh, xw0);
    k_zero <<<1, 128, 0, stream>>>(flags);
    k_fused<<<128, 256, 0, stream>>>(xw0, Wih, Whh, bih, bhh, hf16, hseq, flags);
    k_ln   <<<2048, 256, 0, stream>>>(hseq, gamma, beta, hn);
    k_head <<<dim3(250, 64), 256, 0, stream>>>(hn, wb, headb, out);
}